// Round 12
// baseline (266.151 us; speedup 1.0000x reference)
//
#include <hip/hip_runtime.h>

typedef short short8 __attribute__((ext_vector_type(8)));
typedef float f32x4  __attribute__((ext_vector_type(4)));
typedef unsigned short u16;

#define T_LEN 256
#define NB    8            // samples per block
#define GRID  (2048 / NB)  // 256 blocks, 1/CU
#define LDK   72           // row stride in u16 for 64-col buffers (144 B)

static __device__ __forceinline__ u16 bf16_rne(float f) {
    unsigned u = __builtin_bit_cast(unsigned, f);
    return (u16)((u + 0x7fffu + ((u >> 16) & 1u)) >> 16);
}
static __device__ __forceinline__ float bf16_f(u16 h) {
    unsigned u = ((unsigned)h) << 16;
    return __builtin_bit_cast(float, u);
}
// exact trunc split: f == bf16(hi) + rest; lo = trunc-bf16(rest)
static __device__ __forceinline__ void split_tr(float f, u16& hi, u16& lo) {
    unsigned u = __builtin_bit_cast(unsigned, f);
    hi = (u16)(u >> 16);
    float rest = f - __builtin_bit_cast(float, u & 0xffff0000u);
    lo = (u16)(__builtin_bit_cast(unsigned, rest) >> 16);
}
static __device__ __forceinline__ float fast_sigmoid(float x) {
    float e = __builtin_amdgcn_exp2f(x * -1.4426950408889634f);
    return __builtin_amdgcn_rcpf(1.0f + e);
}
static __device__ __forceinline__ float fast_tanh(float x) {
    float e = __builtin_amdgcn_exp2f(x * -2.8853900817779268f);
    return 2.0f * __builtin_amdgcn_rcpf(1.0f + e) - 1.0f;
}

// ---------------------------------------------------------------------------
// r11 structure (16-wave wave-specialized, split-bf16 MFMA, lo-in-columns,
// shared-H1, peeled boundaries) with ONE change: the hi/lo combine exchange
// runs on the VALU pipe via DPP row_ror:8 (lane l <-> l^8 within 16-rows)
// instead of __shfl_xor on the LDS pipe.  r7's DPP failure read raw MFMA
// accumulators; here the DPP source is a v_cndmask (VALU) result, avoiding
// the MFMA->DPP hazard path.  Final arithmetic bit-identical to r8-r11.
// ---------------------------------------------------------------------------
__global__ __launch_bounds__(1024)
void lstm2_mfma(const float* __restrict__ x,
                const float* __restrict__ W_ih0, const float* __restrict__ W_hh0,
                const float* __restrict__ b_ih0, const float* __restrict__ b_hh0,
                const float* __restrict__ W_ih1, const float* __restrict__ W_hh1,
                const float* __restrict__ b_ih1, const float* __restrict__ b_hh1,
                const float* __restrict__ fc_w,  const float* __restrict__ fc_b,
                float* __restrict__ out)
{
    const int tid = threadIdx.x;
    const int l   = tid & 63;
    const int w   = tid >> 6;      // wave 0..15
    const int grp = w >> 3;        // 0 = layer0, 1 = layer1
    const int wl  = w & 7;         // wave-in-group 0..7
    const int ln  = l & 15;        // C col / frag row
    const int kg  = l >> 4;        // 0..3

    __shared__ __align__(16) u16 XB[2][16][LDK];
    __shared__ __align__(16) u16 H1[2][16][LDK];
    __shared__ __align__(16) u16 H2[2][16][LDK];
    __shared__ __align__(16) float hfin[NB][68];

    // ---- A fragments (my layer, 2 mtiles): RNE hi + lo ----
    short8 Ah[2][4], Al[2][4];
    f32x4  biasv[2];
    {
        const float* Wi = grp ? W_ih1 : W_ih0;
        const float* Wh = grp ? W_hh1 : W_hh0;
        const float* bi = grp ? b_ih1 : b_ih0;
        const float* bh = grp ? b_hh1 : b_hh0;
        #pragma unroll
        for (int mt = 0; mt < 2; ++mt) {
            #pragma unroll
            for (int kt = 0; kt < 4; ++kt) {
                const int uu   = ln >> 2;
                const int gate = ln & 3;
                const int row  = gate * 64 + (wl * 8 + mt * 4 + uu);
                const int kb   = kt * 32 + kg * 8;
                const float* src = (kb < 64) ? (Wi + (size_t)row * 64 + kb)
                                             : (Wh + (size_t)row * 64 + (kb - 64));
                short8 h8, l8;
                #pragma unroll
                for (int j = 0; j < 8; ++j) {
                    float v = src[j];
                    u16 hh = bf16_rne(v);
                    u16 ll = bf16_rne(v - bf16_f(hh));
                    h8[j] = (short)hh; l8[j] = (short)ll;
                }
                Ah[mt][kt] = h8; Al[mt][kt] = l8;
            }
            f32x4 bv;
            #pragma unroll
            for (int r = 0; r < 4; ++r) {
                const int row = r * 64 + (wl * 8 + mt * 4 + kg);
                bv[r] = bi[row] + bh[row];
            }
            biasv[mt] = bv;
        }
    }

    // ---- zero operand LDS (h states start at 0) ----
    {
        u16* p0 = &XB[0][0][0];
        u16* p1 = &H1[0][0][0];
        u16* p2 = &H2[0][0][0];
        const int tot = 2 * 16 * LDK;
        for (int i = tid; i < tot; i += 1024) { p0[i] = 0; p1[i] = 0; p2[i] = 0; }
    }
    __syncthreads();

    const int    sb    = blockIdx.x * NB;
    const int    xs    = (tid >> 6) & 7;   // staging sample (threads 0..511)
    const int    xj    = tid & 63;
    const bool   stg   = (tid < 512);      // wave-uniform (grp0 stages)
    const size_t xbase = ((size_t)(sb + xs)) * T_LEN * 64 + xj;

    if (stg) {   // stage x(0) into XB[0]
        u16 hh, ll; split_tr(x[xbase], hh, ll);
        XB[0][xs][xj]     = hh;
        XB[0][8 + xs][xj] = ll;
    }
    __syncthreads();

    // packed-lane identity for activations/updates
    const int  mtl  = (ln >> 3) & 1;       // 0: mt0 value, 1: mt1 value
    const int  smp  = ln & 7;              // sample
    const int  un   = wl * 8 + mtl * 4 + kg;
    const bool lo8  = (ln < 8);
    float cstate = 0.f;
    float xcur = stg ? x[xbase + 64] : 0.f;   // x(1)

#define MFMA(A, B, C) __builtin_amdgcn_mfma_f32_16x16x32_bf16(A, B, C, 0, 0, 0)

// STEPB(T, G0, G1, STG_ON, XLOAD, FIN): G0/G1 = group active (compile-time),
// STG_ON = stage x(T+1), XLOAD = prefetch x(T+2), FIN = record hfin (grp1).
#define STEPB(T, G0, G1, STG_ON, XLOAD, FIN)                                 \
    do {                                                                     \
        const int p_ = (T) & 1, q_ = p_ ^ 1;                                 \
        float xnext_ = 0.f;                                                  \
        if ((XLOAD) && stg) xnext_ = x[xbase + (size_t)((T) + 2) * 64];      \
        const bool act_ = grp ? (bool)(G1) : (bool)(G0);                     \
        if (act_) {                                                          \
            const u16 (*BA)[LDK] = grp ? H1[p_] : XB[p_];                    \
            const u16 (*BB)[LDK] = grp ? H2[p_] : H1[p_];                    \
            short8 b0 = *(const short8*)&BA[ln][kg * 8];                     \
            short8 b1 = *(const short8*)&BA[ln][32 + kg * 8];                \
            short8 b2 = *(const short8*)&BB[ln][kg * 8];                     \
            short8 b3 = *(const short8*)&BB[ln][32 + kg * 8];                \
            f32x4 aH0 = {0.f,0.f,0.f,0.f}, aH1 = {0.f,0.f,0.f,0.f};          \
            f32x4 aL0 = biasv[0],          aL1 = biasv[1];                   \
            aH0 = MFMA(Ah[0][0], b0, aH0);  aH1 = MFMA(Ah[1][0], b0, aH1);   \
            aL0 = MFMA(Al[0][0], b0, aL0);  aL1 = MFMA(Al[1][0], b0, aL1);   \
            aH0 = MFMA(Ah[0][1], b1, aH0);  aH1 = MFMA(Ah[1][1], b1, aH1);   \
            aL0 = MFMA(Al[0][1], b1, aL0);  aL1 = MFMA(Al[1][1], b1, aL1);   \
            aH0 = MFMA(Ah[0][2], b2, aH0);  aH1 = MFMA(Ah[1][2], b2, aH1);   \
            aL0 = MFMA(Al[0][2], b2, aL0);  aL1 = MFMA(Al[1][2], b2, aL1);   \
            aH0 = MFMA(Ah[0][3], b3, aH0);  aH1 = MFMA(Ah[1][3], b3, aH1);   \
            aL0 = MFMA(Al[0][3], b3, aL0);  aL1 = MFMA(Al[1][3], b3, aL1);   \
            f32x4 pk;                                                        \
            _Pragma("unroll")                                                \
            for (int r = 0; r < 4; ++r) {                                    \
                float u1_   = aH1[r] + aL1[r];          /* VALU */           \
                float send_ = lo8 ? u1_ : aH0[r];       /* v_cndmask */      \
                int   si_   = __builtin_bit_cast(int, send_);                \
                int   ri_   = __builtin_amdgcn_mov_dpp(si_, 0x128, 0xf, 0xf, \
                                                       true); /* ror:8 */    \
                float recv_ = __builtin_bit_cast(float, ri_);                \
                pk[r] = lo8 ? (aH0[r] + recv_ + aL0[r]) : (aH1[r] + recv_);  \
            }                                                                \
            const float ig = fast_sigmoid(pk[0]);                            \
            const float fg = fast_sigmoid(pk[1]);                            \
            const float gg = fast_tanh(pk[2]);                               \
            const float og = fast_sigmoid(pk[3]);                            \
            const float cc = fg * cstate + ig * gg;                          \
            cstate = cc;                                                     \
            const float hv = og * fast_tanh(cc);                             \
            u16 hh_, ll_; split_tr(hv, hh_, ll_);                            \
            if (grp == 0) {                                                  \
                H1[q_][smp][un]     = hh_;                                   \
                H1[q_][8 + smp][un] = ll_;                                   \
            } else {                                                         \
                H2[q_][smp][un]     = hh_;                                   \
                H2[q_][8 + smp][un] = ll_;                                   \
                if (FIN) hfin[smp][un] = hv;                                 \
            }                                                                \
        }                                                                    \
        if ((STG_ON) && stg) {                                               \
            u16 hh_, ll_; split_tr(xcur, hh_, ll_);                          \
            XB[q_][xs][xj]     = hh_;                                        \
            XB[q_][8 + xs][xj] = ll_;                                        \
        }                                                                    \
        xcur = xnext_;                                                       \
        __syncthreads();                                                     \
    } while (0)

    // t = 0: grp0 only; stage x(1); prefetch x(2)
    STEPB(0, 1, 0, 1, 1, 0);
    // main loop t = 1..253: both groups, staging + prefetch, branch-free
    #pragma unroll 1
    for (int t = 1; t <= 253; ++t) {
        STEPB(t, 1, 1, 1, 1, 0);
    }
    // t = 254: both groups, stage x(255), no further prefetch
    STEPB(254, 1, 1, 1, 0, 0);
    // t = 255: both groups, no staging
    STEPB(255, 1, 1, 0, 0, 0);
    // t = 256: grp1 finishes layer-1 step 255, records hfin
    STEPB(256, 0, 1, 0, 0, 1);
#undef STEPB
#undef MFMA

    // ---- FC head: waves 0-7, wave w reduces sample w ----
    if (w < 8) {
        float v = hfin[w][l] * fc_w[l];
        #pragma unroll
        for (int off = 32; off; off >>= 1) v += __shfl_xor(v, off, 64);
        if (l == 0) out[sb + w] = v + fc_b[0];
    }
}

extern "C" void kernel_launch(void* const* d_in, const int* in_sizes, int n_in,
                              void* d_out, int out_size, void* d_ws, size_t ws_size,
                              hipStream_t stream) {
    const float* x     = (const float*)d_in[0];
    const float* W_ih0 = (const float*)d_in[1];
    const float* W_hh0 = (const float*)d_in[2];
    const float* b_ih0 = (const float*)d_in[3];
    const float* b_hh0 = (const float*)d_in[4];
    const float* W_ih1 = (const float*)d_in[5];
    const float* W_hh1 = (const float*)d_in[6];
    const float* b_ih1 = (const float*)d_in[7];
    const float* b_hh1 = (const float*)d_in[8];
    const float* fc_w  = (const float*)d_in[9];
    const float* fc_b  = (const float*)d_in[10];
    float* out = (float*)d_out;

    lstm2_mfma<<<GRID, 1024, 0, stream>>>(x, W_ih0, W_hh0, b_ih0, b_hh0,
                                          W_ih1, W_hh1, b_ih1, b_hh1,
                                          fc_w, fc_b, out);
}

// Round 13
// 238.453 us; speedup vs baseline: 1.1162x; 1.1162x over previous
//
#include <hip/hip_runtime.h>

typedef short short8 __attribute__((ext_vector_type(8)));
typedef float f32x4  __attribute__((ext_vector_type(4)));
typedef unsigned short u16;

#define T_LEN 256
#define NB    8            // samples per block
#define GRID  (2048 / NB)  // 256 blocks, 1/CU
#define LDK   72           // row stride in u16 for 64-col buffers (144 B)

static __device__ __forceinline__ u16 bf16_rne(float f) {
    unsigned u = __builtin_bit_cast(unsigned, f);
    return (u16)((u + 0x7fffu + ((u >> 16) & 1u)) >> 16);
}
static __device__ __forceinline__ float bf16_f(u16 h) {
    unsigned u = ((unsigned)h) << 16;
    return __builtin_bit_cast(float, u);
}
// exact trunc split: f == bf16(hi) + rest; lo = trunc-bf16(rest)
static __device__ __forceinline__ void split_tr(float f, u16& hi, u16& lo) {
    unsigned u = __builtin_bit_cast(unsigned, f);
    hi = (u16)(u >> 16);
    float rest = f - __builtin_bit_cast(float, u & 0xffff0000u);
    lo = (u16)(__builtin_bit_cast(unsigned, rest) >> 16);
}
static __device__ __forceinline__ float fast_sigmoid(float x) {
    float e = __builtin_amdgcn_exp2f(x * -1.4426950408889634f);
    return __builtin_amdgcn_rcpf(1.0f + e);
}
static __device__ __forceinline__ float fast_tanh(float x) {
    float e = __builtin_amdgcn_exp2f(x * -2.8853900817779268f);
    return 2.0f * __builtin_amdgcn_rcpf(1.0f + e) - 1.0f;
}

// ---------------------------------------------------------------------------
// r12 structure (16-wave wave-specialized, split-bf16 MFMA, lo-in-columns,
// shared-H1, DPP combine) with three changes:
//  (1) main loop unrolled x2 with LITERAL parity -> all LDS indices are
//      compile-time expressions on direct __shared__ arrays (no runtime
//      parity selects; r10's generic-pointer trap avoided),
//  (2) single MFMA chain per mtile (Ah and Al accumulate into one acc;
//      adds harmless O(2^-18) Al*lo term; init = lo8 ? bias : 0, hoisted;
//      combine is 4 VALU ops per C row),
//  (3) x staging moved to grp1 (balances grp0's heavier compute path).
// ---------------------------------------------------------------------------
__global__ __launch_bounds__(1024)
void lstm2_mfma(const float* __restrict__ x,
                const float* __restrict__ W_ih0, const float* __restrict__ W_hh0,
                const float* __restrict__ b_ih0, const float* __restrict__ b_hh0,
                const float* __restrict__ W_ih1, const float* __restrict__ W_hh1,
                const float* __restrict__ b_ih1, const float* __restrict__ b_hh1,
                const float* __restrict__ fc_w,  const float* __restrict__ fc_b,
                float* __restrict__ out)
{
    const int tid = threadIdx.x;
    const int l   = tid & 63;
    const int w   = tid >> 6;      // wave 0..15
    const int grp = w >> 3;        // 0 = layer0, 1 = layer1
    const int wl  = w & 7;         // wave-in-group 0..7
    const int ln  = l & 15;        // C col / frag row
    const int kg  = l >> 4;        // 0..3

    __shared__ __align__(16) u16 XB[2][16][LDK];
    __shared__ __align__(16) u16 H1[2][16][LDK];
    __shared__ __align__(16) u16 H2[2][16][LDK];
    __shared__ __align__(16) float hfin[NB][68];

    // ---- A fragments (my layer, 2 mtiles): RNE hi + lo ----
    short8 Ah[2][4], Al[2][4];
    f32x4  biasv[2];
    {
        const float* Wi = grp ? W_ih1 : W_ih0;
        const float* Wh = grp ? W_hh1 : W_hh0;
        const float* bi = grp ? b_ih1 : b_ih0;
        const float* bh = grp ? b_hh1 : b_hh0;
        #pragma unroll
        for (int mt = 0; mt < 2; ++mt) {
            #pragma unroll
            for (int kt = 0; kt < 4; ++kt) {
                const int uu   = ln >> 2;
                const int gate = ln & 3;
                const int row  = gate * 64 + (wl * 8 + mt * 4 + uu);
                const int kb   = kt * 32 + kg * 8;
                const float* src = (kb < 64) ? (Wi + (size_t)row * 64 + kb)
                                             : (Wh + (size_t)row * 64 + (kb - 64));
                short8 h8, l8;
                #pragma unroll
                for (int j = 0; j < 8; ++j) {
                    float v = src[j];
                    u16 hh = bf16_rne(v);
                    u16 ll = bf16_rne(v - bf16_f(hh));
                    h8[j] = (short)hh; l8[j] = (short)ll;
                }
                Ah[mt][kt] = h8; Al[mt][kt] = l8;
            }
            f32x4 bv;
            #pragma unroll
            for (int r = 0; r < 4; ++r) {
                const int row = r * 64 + (wl * 8 + mt * 4 + kg);
                bv[r] = bi[row] + bh[row];
            }
            biasv[mt] = bv;
        }
    }

    // ---- zero operand LDS (h states start at 0) ----
    {
        u16* p0 = &XB[0][0][0];
        u16* p1 = &H1[0][0][0];
        u16* p2 = &H2[0][0][0];
        const int tot = 2 * 16 * LDK;
        for (int i = tid; i < tot; i += 1024) { p0[i] = 0; p1[i] = 0; p2[i] = 0; }
    }
    __syncthreads();

    const int    sb    = blockIdx.x * NB;
    const bool   stg   = (grp == 1);       // staging on grp1 (balance)
    const int    xs    = wl;               // staging sample
    const int    xj    = l;                // staging k index
    const size_t xbase = ((size_t)(sb + xs)) * T_LEN * 64 + xj;

    if (stg) {   // stage x(0) into XB[0]
        u16 hh, ll; split_tr(x[xbase], hh, ll);
        XB[0][xs][xj]     = hh;
        XB[0][8 + xs][xj] = ll;
    }
    __syncthreads();

    // packed-lane identity for activations/updates
    const int  mtl  = (ln >> 3) & 1;       // 0: mt0 value, 1: mt1 value
    const int  smp  = ln & 7;              // sample
    const int  un   = wl * 8 + mtl * 4 + kg;
    const bool lo8  = (ln < 8);
    const f32x4 zv  = {0.f, 0.f, 0.f, 0.f};
    const f32x4 init0 = lo8 ? biasv[0] : zv;   // bias only in hi columns
    const f32x4 init1 = lo8 ? biasv[1] : zv;
    float cstate = 0.f;
    float xcur = stg ? x[xbase + 64] : 0.f;    // x(1)

#define MFMA(A, B, C) __builtin_amdgcn_mfma_f32_16x16x32_bf16(A, B, C, 0, 0, 0)

// STEPB(T, P, G0, G1, STG_ON, XLOAD, FIN): P = LITERAL read parity,
// G0/G1 group-active, STG_ON = stage x(T+1), XLOAD = prefetch x(T+2),
// FIN = record hfin (grp1).
#define STEPB(T, P, G0, G1, STG_ON, XLOAD, FIN)                              \
    do {                                                                     \
        float xnext_ = 0.f;                                                  \
        if ((XLOAD) && stg) xnext_ = x[xbase + (size_t)((T) + 2) * 64];      \
        const bool act_ = grp ? (bool)(G1) : (bool)(G0);                     \
        if (act_) {                                                          \
            short8 b0, b1, b2, b3;                                           \
            if (grp) {                                                       \
                b0 = *(const short8*)&H1[P][ln][kg * 8];                     \
                b1 = *(const short8*)&H1[P][ln][32 + kg * 8];                \
                b2 = *(const short8*)&H2[P][ln][kg * 8];                     \
                b3 = *(const short8*)&H2[P][ln][32 + kg * 8];                \
            } else {                                                         \
                b0 = *(const short8*)&XB[P][ln][kg * 8];                     \
                b1 = *(const short8*)&XB[P][ln][32 + kg * 8];                \
                b2 = *(const short8*)&H1[P][ln][kg * 8];                     \
                b3 = *(const short8*)&H1[P][ln][32 + kg * 8];                \
            }                                                                \
            f32x4 a0 = init0, a1 = init1;                                    \
            a0 = MFMA(Ah[0][0], b0, a0);  a1 = MFMA(Ah[1][0], b0, a1);       \
            a0 = MFMA(Al[0][0], b0, a0);  a1 = MFMA(Al[1][0], b0, a1);       \
            a0 = MFMA(Ah[0][1], b1, a0);  a1 = MFMA(Ah[1][1], b1, a1);       \
            a0 = MFMA(Al[0][1], b1, a0);  a1 = MFMA(Al[1][1], b1, a1);       \
            a0 = MFMA(Ah[0][2], b2, a0);  a1 = MFMA(Ah[1][2], b2, a1);       \
            a0 = MFMA(Al[0][2], b2, a0);  a1 = MFMA(Al[1][2], b2, a1);       \
            a0 = MFMA(Ah[0][3], b3, a0);  a1 = MFMA(Ah[1][3], b3, a1);       \
            a0 = MFMA(Al[0][3], b3, a0);  a1 = MFMA(Al[1][3], b3, a1);       \
            f32x4 pk;                                                        \
            _Pragma("unroll")                                                \
            for (int r = 0; r < 4; ++r) {                                    \
                float send_ = lo8 ? a1[r] : a0[r];      /* v_cndmask */      \
                int   si_   = __builtin_bit_cast(int, send_);                \
                int   ri_   = __builtin_amdgcn_mov_dpp(si_, 0x128, 0xf, 0xf, \
                                                       true); /* ror:8 */    \
                float recv_ = __builtin_bit_cast(float, ri_);                \
                float self_ = lo8 ? a0[r] : a1[r];                           \
                pk[r] = self_ + recv_;                                       \
            }                                                                \
            const float ig = fast_sigmoid(pk[0]);                            \
            const float fg = fast_sigmoid(pk[1]);                            \
            const float gg = fast_tanh(pk[2]);                               \
            const float og = fast_sigmoid(pk[3]);                            \
            const float cc = fg * cstate + ig * gg;                          \
            cstate = cc;                                                     \
            const float hv = og * fast_tanh(cc);                             \
            u16 hh_, ll_; split_tr(hv, hh_, ll_);                            \
            if (grp == 0) {                                                  \
                H1[1 - (P)][smp][un]     = hh_;                              \
                H1[1 - (P)][8 + smp][un] = ll_;                              \
            } else {                                                         \
                H2[1 - (P)][smp][un]     = hh_;                              \
                H2[1 - (P)][8 + smp][un] = ll_;                              \
                if (FIN) hfin[smp][un] = hv;                                 \
            }                                                                \
        }                                                                    \
        if ((STG_ON) && stg) {                                               \
            u16 hh_, ll_; split_tr(xcur, hh_, ll_);                          \
            XB[1 - (P)][xs][xj]     = hh_;                                   \
            XB[1 - (P)][8 + xs][xj] = ll_;                                   \
        }                                                                    \
        xcur = xnext_;                                                       \
        __syncthreads();                                                     \
    } while (0)

    // t = 0 (p=0): grp0 only; stage x(1); prefetch x(2)
    STEPB(0, 0, 1, 0, 1, 1, 0);
    // main loop: pairs (odd p=1, even p=0), steps 1..252, branch-free
    #pragma unroll 1
    for (int t = 1; t <= 251; t += 2) {
        STEPB(t,     1, 1, 1, 1, 1, 0);
        STEPB(t + 1, 0, 1, 1, 1, 1, 0);
    }
    // t = 253 (p=1): stage x(254), prefetch x(255)
    STEPB(253, 1, 1, 1, 1, 1, 0);
    // t = 254 (p=0): stage x(255), no further prefetch
    STEPB(254, 0, 1, 1, 1, 0, 0);
    // t = 255 (p=1): no staging
    STEPB(255, 1, 1, 1, 0, 0, 0);
    // t = 256 (p=0): grp1 finishes layer-1 step 255, records hfin
    STEPB(256, 0, 0, 1, 0, 0, 1);
#undef STEPB
#undef MFMA

    // ---- FC head: waves 0-7, wave w reduces sample w ----
    if (w < 8) {
        float v = hfin[w][l] * fc_w[l];
        #pragma unroll
        for (int off = 32; off; off >>= 1) v += __shfl_xor(v, off, 64);
        if (l == 0) out[sb + w] = v + fc_b[0];
    }
}

extern "C" void kernel_launch(void* const* d_in, const int* in_sizes, int n_in,
                              void* d_out, int out_size, void* d_ws, size_t ws_size,
                              hipStream_t stream) {
    const float* x     = (const float*)d_in[0];
    const float* W_ih0 = (const float*)d_in[1];
    const float* W_hh0 = (const float*)d_in[2];
    const float* b_ih0 = (const float*)d_in[3];
    const float* b_hh0 = (const float*)d_in[4];
    const float* W_ih1 = (const float*)d_in[5];
    const float* W_hh1 = (const float*)d_in[6];
    const float* b_ih1 = (const float*)d_in[7];
    const float* b_hh1 = (const float*)d_in[8];
    const float* fc_w  = (const float*)d_in[9];
    const float* fc_b  = (const float*)d_in[10];
    float* out = (float*)d_out;

    lstm2_mfma<<<GRID, 1024, 0, stream>>>(x, W_ih0, W_hh0, b_ih0, b_hh0,
                                          W_ih1, W_hh1, b_ih1, b_hh1,
                                          fc_w, fc_b, out);
}

// Round 14
// 238.252 us; speedup vs baseline: 1.1171x; 1.0008x over previous
//
#include <hip/hip_runtime.h>

typedef short short8 __attribute__((ext_vector_type(8)));
typedef float f32x4  __attribute__((ext_vector_type(4)));
typedef unsigned short u16;

#define T_LEN 256
#define NB    8            // samples per block
#define GRID  (2048 / NB)  // 256 blocks, 1/CU
#define LDK   72           // row stride in u16 for 64-col buffers (144 B)

static __device__ __forceinline__ u16 bf16_rne(float f) {
    unsigned u = __builtin_bit_cast(unsigned, f);
    return (u16)((u + 0x7fffu + ((u >> 16) & 1u)) >> 16);
}
static __device__ __forceinline__ float bf16_f(u16 h) {
    unsigned u = ((unsigned)h) << 16;
    return __builtin_bit_cast(float, u);
}
// exact trunc split: f == bf16(hi) + rest; lo = trunc-bf16(rest)
static __device__ __forceinline__ void split_tr(float f, u16& hi, u16& lo) {
    unsigned u = __builtin_bit_cast(unsigned, f);
    hi = (u16)(u >> 16);
    float rest = f - __builtin_bit_cast(float, u & 0xffff0000u);
    lo = (u16)(__builtin_bit_cast(unsigned, rest) >> 16);
}
static __device__ __forceinline__ float fast_sigmoid(float x) {
    float e = __builtin_amdgcn_exp2f(x * -1.4426950408889634f);
    return __builtin_amdgcn_rcpf(1.0f + e);
}
static __device__ __forceinline__ float fast_tanh(float x) {
    float e = __builtin_amdgcn_exp2f(x * -2.8853900817779268f);
    return 2.0f * __builtin_amdgcn_rcpf(1.0f + e) - 1.0f;
}

// ---------------------------------------------------------------------------
// ANTI-PHASE two-phase schedule on the r13 structure (16-wave specialized,
// split-bf16 MFMA, lo-in-columns, single-chain-per-mtile, DPP combine,
// literal parity).  Per iteration T (two barriers):
//   P1: grp0 = ds_read+MFMA+combine for layer0 step T
//       grp1 = activations+H2 write for layer1 step T-2, + x staging
//   P2: grp0 = activations+H1[1-P] write for step T
//       grp1 = ds_read+MFMA+combine for layer1 step T-1 (reads H1[P], H2)
// At any instant each SIMD has 2 waves on LDS/MFMA and 2 on VALU/trans --
// smooths the former lockstep bursts.  H2 single-buffered (write P1/read P2,
// WAR split by barrier2).  H1/XB parity-double-buffered as before.
// Iterations 0..257 (grp1 ACT trails by 2); boundary iterations peeled.
// ---------------------------------------------------------------------------
__global__ __launch_bounds__(1024)
void lstm2_mfma(const float* __restrict__ x,
                const float* __restrict__ W_ih0, const float* __restrict__ W_hh0,
                const float* __restrict__ b_ih0, const float* __restrict__ b_hh0,
                const float* __restrict__ W_ih1, const float* __restrict__ W_hh1,
                const float* __restrict__ b_ih1, const float* __restrict__ b_hh1,
                const float* __restrict__ fc_w,  const float* __restrict__ fc_b,
                float* __restrict__ out)
{
    const int tid = threadIdx.x;
    const int l   = tid & 63;
    const int w   = tid >> 6;      // wave 0..15
    const int grp = w >> 3;        // 0 = layer0, 1 = layer1
    const int wl  = w & 7;         // wave-in-group 0..7
    const int ln  = l & 15;        // C col / frag row
    const int kg  = l >> 4;        // 0..3

    __shared__ __align__(16) u16 XB[2][16][LDK];
    __shared__ __align__(16) u16 H1[2][16][LDK];
    __shared__ __align__(16) u16 H2[16][LDK];      // single buffer
    __shared__ __align__(16) float hfin[NB][68];

    // ---- A fragments (my layer, 2 mtiles): RNE hi + lo ----
    short8 Ah[2][4], Al[2][4];
    f32x4  biasv[2];
    {
        const float* Wi = grp ? W_ih1 : W_ih0;
        const float* Wh = grp ? W_hh1 : W_hh0;
        const float* bi = grp ? b_ih1 : b_ih0;
        const float* bh = grp ? b_hh1 : b_hh0;
        #pragma unroll
        for (int mt = 0; mt < 2; ++mt) {
            #pragma unroll
            for (int kt = 0; kt < 4; ++kt) {
                const int uu   = ln >> 2;
                const int gate = ln & 3;
                const int row  = gate * 64 + (wl * 8 + mt * 4 + uu);
                const int kb   = kt * 32 + kg * 8;
                const float* src = (kb < 64) ? (Wi + (size_t)row * 64 + kb)
                                             : (Wh + (size_t)row * 64 + (kb - 64));
                short8 h8, l8;
                #pragma unroll
                for (int j = 0; j < 8; ++j) {
                    float v = src[j];
                    u16 hh = bf16_rne(v);
                    u16 ll = bf16_rne(v - bf16_f(hh));
                    h8[j] = (short)hh; l8[j] = (short)ll;
                }
                Ah[mt][kt] = h8; Al[mt][kt] = l8;
            }
            f32x4 bv;
            #pragma unroll
            for (int r = 0; r < 4; ++r) {
                const int row = r * 64 + (wl * 8 + mt * 4 + kg);
                bv[r] = bi[row] + bh[row];
            }
            biasv[mt] = bv;
        }
    }

    // ---- zero operand LDS (h states start at 0) ----
    {
        u16* p0 = &XB[0][0][0];
        u16* p1 = &H1[0][0][0];
        const int tot2 = 2 * 16 * LDK;
        for (int i = tid; i < tot2; i += 1024) { p0[i] = 0; p1[i] = 0; }
        u16* p2 = &H2[0][0];
        const int tot1 = 16 * LDK;
        for (int i = tid; i < tot1; i += 1024) p2[i] = 0;
    }
    __syncthreads();

    const int    sb    = blockIdx.x * NB;
    const bool   stg   = (grp == 1);       // staging on grp1 (P1 role)
    const int    xs    = wl;               // staging sample
    const int    xj    = l;                // staging k index
    const size_t xbase = ((size_t)(sb + xs)) * T_LEN * 64 + xj;

    if (stg) {   // stage x(0) into XB[0]
        u16 hh, ll; split_tr(x[xbase], hh, ll);
        XB[0][xs][xj]     = hh;
        XB[0][8 + xs][xj] = ll;
    }
    __syncthreads();

    // packed-lane identity for activations/updates
    const int  mtl  = (ln >> 3) & 1;       // 0: mt0 value, 1: mt1 value
    const int  smp  = ln & 7;              // sample
    const int  un   = wl * 8 + mtl * 4 + kg;
    const bool lo8  = (ln < 8);
    const f32x4 zv  = {0.f, 0.f, 0.f, 0.f};
    const f32x4 init0 = lo8 ? biasv[0] : zv;   // bias only in hi columns
    const f32x4 init1 = lo8 ? biasv[1] : zv;
    float cstate = 0.f;
    f32x4 pk = zv;                             // persists across barriers
    float xcur = stg ? x[xbase + 64] : 0.f;    // x(1)

#define MFMA(A, B, C) __builtin_amdgcn_mfma_f32_16x16x32_bf16(A, B, C, 0, 0, 0)

#define MFMA16(b0, b1, b2, b3)                                               \
            f32x4 a0 = init0, a1 = init1;                                    \
            a0 = MFMA(Ah[0][0], b0, a0);  a1 = MFMA(Ah[1][0], b0, a1);       \
            a0 = MFMA(Al[0][0], b0, a0);  a1 = MFMA(Al[1][0], b0, a1);       \
            a0 = MFMA(Ah[0][1], b1, a0);  a1 = MFMA(Ah[1][1], b1, a1);       \
            a0 = MFMA(Al[0][1], b1, a0);  a1 = MFMA(Al[1][1], b1, a1);       \
            a0 = MFMA(Ah[0][2], b2, a0);  a1 = MFMA(Ah[1][2], b2, a1);       \
            a0 = MFMA(Al[0][2], b2, a0);  a1 = MFMA(Al[1][2], b2, a1);       \
            a0 = MFMA(Ah[0][3], b3, a0);  a1 = MFMA(Ah[1][3], b3, a1);       \
            a0 = MFMA(Al[0][3], b3, a0);  a1 = MFMA(Al[1][3], b3, a1);       \
            _Pragma("unroll")                                                \
            for (int r = 0; r < 4; ++r) {                                    \
                float send_ = lo8 ? a1[r] : a0[r];      /* v_cndmask */      \
                int   si_   = __builtin_bit_cast(int, send_);                \
                int   ri_   = __builtin_amdgcn_mov_dpp(si_, 0x128, 0xf, 0xf, \
                                                       true); /* ror:8 */    \
                float recv_ = __builtin_bit_cast(float, ri_);                \
                float self_ = lo8 ? a0[r] : a1[r];                           \
                pk[r] = self_ + recv_;                                       \
            }

#define ACTBODY                                                              \
            const float ig_ = fast_sigmoid(pk[0]);                           \
            const float fg_ = fast_sigmoid(pk[1]);                           \
            const float gg_ = fast_tanh(pk[2]);                              \
            const float og_ = fast_sigmoid(pk[3]);                           \
            const float cc_ = fg_ * cstate + ig_ * gg_;                      \
            cstate = cc_;                                                    \
            const float hv_ = og_ * fast_tanh(cc_);                          \
            u16 hh_, ll_; split_tr(hv_, hh_, ll_)

// STEP2(T, P, G0, G1M, G1A, STG_ON, XLOAD, FIN): P = LITERAL parity.
#define STEP2(T, P, G0, G1M, G1A, STG_ON, XLOAD, FIN)                        \
    do {                                                                     \
        float xnext_ = 0.f;                                                  \
        /* ------------- PHASE 1 ------------- */                            \
        if (grp == 0) {                                                      \
            if (G0) {                                                        \
                short8 b0 = *(const short8*)&XB[P][ln][kg * 8];              \
                short8 b1 = *(const short8*)&XB[P][ln][32 + kg * 8];         \
                short8 b2 = *(const short8*)&H1[P][ln][kg * 8];              \
                short8 b3 = *(const short8*)&H1[P][ln][32 + kg * 8];         \
                MFMA16(b0, b1, b2, b3);                                      \
            }                                                                \
        } else {                                                             \
            if (XLOAD) xnext_ = x[xbase + (size_t)((T) + 2) * 64];           \
            if (G1A) {              /* layer1 step T-2 */                    \
                ACTBODY;                                                     \
                H2[smp][un]     = hh_;                                       \
                H2[8 + smp][un] = ll_;                                       \
                if (FIN) hfin[smp][un] = hv_;                                \
            }                                                                \
            if (STG_ON) {           /* stage x(T+1) */                       \
                u16 hh_, ll_; split_tr(xcur, hh_, ll_);                      \
                XB[1 - (P)][xs][xj]     = hh_;                               \
                XB[1 - (P)][8 + xs][xj] = ll_;                               \
            }                                                                \
        }                                                                    \
        __syncthreads();                                                     \
        /* ------------- PHASE 2 ------------- */                            \
        if (grp == 0) {                                                      \
            if (G0) {               /* layer0 step T finish */               \
                ACTBODY;                                                     \
                H1[1 - (P)][smp][un]     = hh_;                              \
                H1[1 - (P)][8 + smp][un] = ll_;                              \
            }                                                                \
        } else {                                                             \
            if (G1M) {              /* layer1 step T-1 MFMA */               \
                short8 b0 = *(const short8*)&H1[P][ln][kg * 8];              \
                short8 b1 = *(const short8*)&H1[P][ln][32 + kg * 8];         \
                short8 b2 = *(const short8*)&H2[ln][kg * 8];                 \
                short8 b3 = *(const short8*)&H2[ln][32 + kg * 8];            \
                MFMA16(b0, b1, b2, b3);                                      \
            }                                                                \
            xcur = xnext_;                                                   \
        }                                                                    \
        __syncthreads();                                                     \
    } while (0)

    // pipeline fill: iters 0..2
    STEP2(0, 0, 1, 0, 0, 1, 1, 0);
    STEP2(1, 1, 1, 1, 0, 1, 1, 0);
    STEP2(2, 0, 1, 1, 1, 1, 1, 0);
    // main loop: iters 3..252, fully active, literal parity pairs
    #pragma unroll 1
    for (int t = 3; t <= 251; t += 2) {
        STEP2(t,     1, 1, 1, 1, 1, 1, 0);
        STEP2(t + 1, 0, 1, 1, 1, 1, 1, 0);
    }
    // pipeline drain: iters 253..257
    STEP2(253, 1, 1, 1, 1, 1, 1, 0);
    STEP2(254, 0, 1, 1, 1, 1, 0, 0);
    STEP2(255, 1, 1, 1, 1, 0, 0, 0);
    STEP2(256, 0, 0, 1, 1, 0, 0, 0);
    STEP2(257, 1, 0, 0, 1, 0, 0, 1);
#undef STEP2
#undef ACTBODY
#undef MFMA16
#undef MFMA

    // ---- FC head: waves 0-7, wave w reduces sample w ----
    if (w < 8) {
        float v = hfin[w][l] * fc_w[l];
        #pragma unroll
        for (int off = 32; off; off >>= 1) v += __shfl_xor(v, off, 64);
        if (l == 0) out[sb + w] = v + fc_b[0];
    }
}

extern "C" void kernel_launch(void* const* d_in, const int* in_sizes, int n_in,
                              void* d_out, int out_size, void* d_ws, size_t ws_size,
                              hipStream_t stream) {
    const float* x     = (const float*)d_in[0];
    const float* W_ih0 = (const float*)d_in[1];
    const float* W_hh0 = (const float*)d_in[2];
    const float* b_ih0 = (const float*)d_in[3];
    const float* b_hh0 = (const float*)d_in[4];
    const float* W_ih1 = (const float*)d_in[5];
    const float* W_hh1 = (const float*)d_in[6];
    const float* b_ih1 = (const float*)d_in[7];
    const float* b_hh1 = (const float*)d_in[8];
    const float* fc_w  = (const float*)d_in[9];
    const float* fc_b  = (const float*)d_in[10];
    float* out = (float*)d_out;

    lstm2_mfma<<<GRID, 1024, 0, stream>>>(x, W_ih0, W_hh0, b_ih0, b_hh0,
                                          W_ih1, W_hh1, b_ih1, b_hh1,
                                          fc_w, fc_b, out);
}

// Round 15
// 233.770 us; speedup vs baseline: 1.1385x; 1.0192x over previous
//
#include <hip/hip_runtime.h>

typedef short short8 __attribute__((ext_vector_type(8)));
typedef float f32x4  __attribute__((ext_vector_type(4)));
typedef unsigned short u16;

#define T_LEN 256
#define NB    8            // samples per block
#define GRID  (2048 / NB)  // 256 blocks, 1/CU
#define LDK   72           // row stride in u16 for 64-col buffers (144 B)

static __device__ __forceinline__ u16 bf16_rne(float f) {
    unsigned u = __builtin_bit_cast(unsigned, f);
    return (u16)((u + 0x7fffu + ((u >> 16) & 1u)) >> 16);
}
static __device__ __forceinline__ float bf16_f(u16 h) {
    unsigned u = ((unsigned)h) << 16;
    return __builtin_bit_cast(float, u);
}
// exact trunc split: f == bf16(hi) + rest; lo = trunc-bf16(rest)
static __device__ __forceinline__ void split_tr(float f, u16& hi, u16& lo) {
    unsigned u = __builtin_bit_cast(unsigned, f);
    hi = (u16)(u >> 16);
    float rest = f - __builtin_bit_cast(float, u & 0xffff0000u);
    lo = (u16)(__builtin_bit_cast(unsigned, rest) >> 16);
}
// sigma(z) with PRE-SCALED argument z' = -log2(e)*z already applied via weights
static __device__ __forceinline__ float sig_pre(float zp) {
    return __builtin_amdgcn_rcpf(1.0f + __builtin_amdgcn_exp2f(zp));
}
static __device__ __forceinline__ float fast_tanh(float x) {
    float e = __builtin_amdgcn_exp2f(x * -2.8853900817779268f);
    return 2.0f * __builtin_amdgcn_rcpf(1.0f + e) - 1.0f;
}

// ---------------------------------------------------------------------------
// r13 structure (16-wave wave-specialized, split-bf16 MFMA, lo-in-columns,
// shared-H1, single-chain-per-mtile, DPP combine, literal parity, peeled
// boundaries) + INSTRUCTION-COUNT cuts (combined VALU+MFMA issue ~99%
// saturated => fewer instructions is the only lever):
//  (a) activation argument scaling folded into weights/biases at load:
//      gate rows i,f,o scaled by -log2(e), g rows by -2*log2(e);
//      sigma = rcp(1+exp2(z')), tanh = 2*rcp(1+exp2(z''))-1 -- no arg muls.
//  (b) act algebra re-folded: ig*gg = fma(ig*gt,2,-ig); hv = fma(og*r,2,-og).
// ---------------------------------------------------------------------------
__global__ __launch_bounds__(1024)
void lstm2_mfma(const float* __restrict__ x,
                const float* __restrict__ W_ih0, const float* __restrict__ W_hh0,
                const float* __restrict__ b_ih0, const float* __restrict__ b_hh0,
                const float* __restrict__ W_ih1, const float* __restrict__ W_hh1,
                const float* __restrict__ b_ih1, const float* __restrict__ b_hh1,
                const float* __restrict__ fc_w,  const float* __restrict__ fc_b,
                float* __restrict__ out)
{
    const int tid = threadIdx.x;
    const int l   = tid & 63;
    const int w   = tid >> 6;      // wave 0..15
    const int grp = w >> 3;        // 0 = layer0, 1 = layer1
    const int wl  = w & 7;         // wave-in-group 0..7
    const int ln  = l & 15;        // C col / frag row
    const int kg  = l >> 4;        // 0..3

    __shared__ __align__(16) u16 XB[2][16][LDK];
    __shared__ __align__(16) u16 H1[2][16][LDK];
    __shared__ __align__(16) u16 H2[2][16][LDK];
    __shared__ __align__(16) float hfin[NB][68];

    // ---- A fragments (my layer, 2 mtiles): PRE-SCALED, RNE hi + lo ----
    short8 Ah[2][4], Al[2][4];
    f32x4  biasv[2];
    {
        const float* Wi = grp ? W_ih1 : W_ih0;
        const float* Wh = grp ? W_hh1 : W_hh0;
        const float* bi = grp ? b_ih1 : b_ih0;
        const float* bh = grp ? b_hh1 : b_hh0;
        #pragma unroll
        for (int mt = 0; mt < 2; ++mt) {
            #pragma unroll
            for (int kt = 0; kt < 4; ++kt) {
                const int uu   = ln >> 2;
                const int gate = ln & 3;
                const float sc = (gate == 2) ? -2.8853900817779268f
                                             : -1.4426950408889634f;
                const int row  = gate * 64 + (wl * 8 + mt * 4 + uu);
                const int kb   = kt * 32 + kg * 8;
                const float* src = (kb < 64) ? (Wi + (size_t)row * 64 + kb)
                                             : (Wh + (size_t)row * 64 + (kb - 64));
                short8 h8, l8;
                #pragma unroll
                for (int j = 0; j < 8; ++j) {
                    float v = src[j] * sc;
                    u16 hh = bf16_rne(v);
                    u16 ll = bf16_rne(v - bf16_f(hh));
                    h8[j] = (short)hh; l8[j] = (short)ll;
                }
                Ah[mt][kt] = h8; Al[mt][kt] = l8;
            }
            f32x4 bv;
            #pragma unroll
            for (int r = 0; r < 4; ++r) {
                const float sc = (r == 2) ? -2.8853900817779268f
                                          : -1.4426950408889634f;
                const int row = r * 64 + (wl * 8 + mt * 4 + kg);
                bv[r] = (bi[row] + bh[row]) * sc;
            }
            biasv[mt] = bv;
        }
    }

    // ---- zero operand LDS (h states start at 0) ----
    {
        u16* p0 = &XB[0][0][0];
        u16* p1 = &H1[0][0][0];
        u16* p2 = &H2[0][0][0];
        const int tot = 2 * 16 * LDK;
        for (int i = tid; i < tot; i += 1024) { p0[i] = 0; p1[i] = 0; p2[i] = 0; }
    }
    __syncthreads();

    const int    sb    = blockIdx.x * NB;
    const bool   stg   = (grp == 1);       // staging on grp1 (balance)
    const int    xs    = wl;               // staging sample
    const int    xj    = l;                // staging k index
    const size_t xbase = ((size_t)(sb + xs)) * T_LEN * 64 + xj;

    if (stg) {   // stage x(0) into XB[0]
        u16 hh, ll; split_tr(x[xbase], hh, ll);
        XB[0][xs][xj]     = hh;
        XB[0][8 + xs][xj] = ll;
    }
    __syncthreads();

    // packed-lane identity for activations/updates
    const int  mtl  = (ln >> 3) & 1;       // 0: mt0 value, 1: mt1 value
    const int  smp  = ln & 7;              // sample
    const int  un   = wl * 8 + mtl * 4 + kg;
    const bool lo8  = (ln < 8);
    const f32x4 zv  = {0.f, 0.f, 0.f, 0.f};
    const f32x4 init0 = lo8 ? biasv[0] : zv;   // bias only in hi columns
    const f32x4 init1 = lo8 ? biasv[1] : zv;
    float cstate = 0.f;
    float xcur = stg ? x[xbase + 64] : 0.f;    // x(1)

#define MFMA(A, B, C) __builtin_amdgcn_mfma_f32_16x16x32_bf16(A, B, C, 0, 0, 0)

// STEPB(T, P, G0, G1, STG_ON, XLOAD, FIN): P = LITERAL read parity.
#define STEPB(T, P, G0, G1, STG_ON, XLOAD, FIN)                              \
    do {                                                                     \
        float xnext_ = 0.f;                                                  \
        if ((XLOAD) && stg) xnext_ = x[xbase + (size_t)((T) + 2) * 64];      \
        const bool act_ = grp ? (bool)(G1) : (bool)(G0);                     \
        if (act_) {                                                          \
            short8 b0, b1, b2, b3;                                           \
            if (grp) {                                                       \
                b0 = *(const short8*)&H1[P][ln][kg * 8];                     \
                b1 = *(const short8*)&H1[P][ln][32 + kg * 8];                \
                b2 = *(const short8*)&H2[P][ln][kg * 8];                     \
                b3 = *(const short8*)&H2[P][ln][32 + kg * 8];                \
            } else {                                                         \
                b0 = *(const short8*)&XB[P][ln][kg * 8];                     \
                b1 = *(const short8*)&XB[P][ln][32 + kg * 8];                \
                b2 = *(const short8*)&H1[P][ln][kg * 8];                     \
                b3 = *(const short8*)&H1[P][ln][32 + kg * 8];                \
            }                                                                \
            f32x4 a0 = init0, a1 = init1;                                    \
            a0 = MFMA(Ah[0][0], b0, a0);  a1 = MFMA(Ah[1][0], b0, a1);       \
            a0 = MFMA(Al[0][0], b0, a0);  a1 = MFMA(Al[1][0], b0, a1);       \
            a0 = MFMA(Ah[0][1], b1, a0);  a1 = MFMA(Ah[1][1], b1, a1);       \
            a0 = MFMA(Al[0][1], b1, a0);  a1 = MFMA(Al[1][1], b1, a1);       \
            a0 = MFMA(Ah[0][2], b2, a0);  a1 = MFMA(Ah[1][2], b2, a1);       \
            a0 = MFMA(Al[0][2], b2, a0);  a1 = MFMA(Al[1][2], b2, a1);       \
            a0 = MFMA(Ah[0][3], b3, a0);  a1 = MFMA(Ah[1][3], b3, a1);       \
            a0 = MFMA(Al[0][3], b3, a0);  a1 = MFMA(Al[1][3], b3, a1);       \
            f32x4 pk;                                                        \
            _Pragma("unroll")                                                \
            for (int r = 0; r < 4; ++r) {                                    \
                float send_ = lo8 ? a1[r] : a0[r];      /* v_cndmask */      \
                int   si_   = __builtin_bit_cast(int, send_);                \
                int   ri_   = __builtin_amdgcn_mov_dpp(si_, 0x128, 0xf, 0xf, \
                                                       true); /* ror:8 */    \
                float recv_ = __builtin_bit_cast(float, ri_);                \
                float self_ = lo8 ? a0[r] : a1[r];                           \
                pk[r] = self_ + recv_;                                       \
            }                                                                \
            /* pre-scaled gates: no argument muls */                         \
            const float ig  = sig_pre(pk[0]);                                \
            const float fg  = sig_pre(pk[1]);                                \
            const float gt  = sig_pre(pk[2]);      /* sigma(2z) */           \
            const float og  = sig_pre(pk[3]);                                \
            const float igt = ig * gt;                                       \
            const float igg = fmaf(igt, 2.0f, -ig);   /* ig*tanh(z) */       \
            const float cc  = fmaf(fg, cstate, igg);                         \
            cstate = cc;                                                     \
            const float tr_ = __builtin_amdgcn_rcpf(                         \
                1.0f + __builtin_amdgcn_exp2f(cc * -2.8853900817779268f));   \
            const float otr = og * tr_;                                      \
            const float hv  = fmaf(otr, 2.0f, -og);   /* og*tanh(cc) */      \
            u16 hh_, ll_; split_tr(hv, hh_, ll_);                            \
            if (grp == 0) {                                                  \
                H1[1 - (P)][smp][un]     = hh_;                              \
                H1[1 - (P)][8 + smp][un] = ll_;                              \
            } else {                                                         \
                H2[1 - (P)][smp][un]     = hh_;                              \
                H2[1 - (P)][8 + smp][un] = ll_;                              \
                if (FIN) hfin[smp][un] = hv;                                 \
            }                                                                \
        }                                                                    \
        if ((STG_ON) && stg) {                                               \
            u16 hh_, ll_; split_tr(xcur, hh_, ll_);                          \
            XB[1 - (P)][xs][xj]     = hh_;                                   \
            XB[1 - (P)][8 + xs][xj] = ll_;                                   \
        }                                                                    \
        xcur = xnext_;                                                       \
        __syncthreads();                                                     \
    } while (0)

    // t = 0 (p=0): grp0 only; stage x(1); prefetch x(2)
    STEPB(0, 0, 1, 0, 1, 1, 0);
    // main loop: pairs (odd p=1, even p=0), steps 1..252, branch-free
    #pragma unroll 1
    for (int t = 1; t <= 251; t += 2) {
        STEPB(t,     1, 1, 1, 1, 1, 0);
        STEPB(t + 1, 0, 1, 1, 1, 1, 0);
    }
    // t = 253 (p=1): stage x(254), prefetch x(255)
    STEPB(253, 1, 1, 1, 1, 1, 0);
    // t = 254 (p=0): stage x(255), no further prefetch
    STEPB(254, 0, 1, 1, 1, 0, 0);
    // t = 255 (p=1): no staging
    STEPB(255, 1, 1, 1, 0, 0, 0);
    // t = 256 (p=0): grp1 finishes layer-1 step 255, records hfin
    STEPB(256, 0, 0, 1, 0, 0, 1);
#undef STEPB
#undef MFMA

    // ---- FC head: waves 0-7, wave w reduces sample w ----
    if (w < 8) {
        float v = hfin[w][l] * fc_w[l];
        #pragma unroll
        for (int off = 32; off; off >>= 1) v += __shfl_xor(v, off, 64);
        if (l == 0) out[sb + w] = v + fc_b[0];
    }
}

extern "C" void kernel_launch(void* const* d_in, const int* in_sizes, int n_in,
                              void* d_out, int out_size, void* d_ws, size_t ws_size,
                              hipStream_t stream) {
    const float* x     = (const float*)d_in[0];
    const float* W_ih0 = (const float*)d_in[1];
    const float* W_hh0 = (const float*)d_in[2];
    const float* b_ih0 = (const float*)d_in[3];
    const float* b_hh0 = (const float*)d_in[4];
    const float* W_ih1 = (const float*)d_in[5];
    const float* W_hh1 = (const float*)d_in[6];
    const float* b_ih1 = (const float*)d_in[7];
    const float* b_hh1 = (const float*)d_in[8];
    const float* fc_w  = (const float*)d_in[9];
    const float* fc_b  = (const float*)d_in[10];
    float* out = (float*)d_out;

    lstm2_mfma<<<GRID, 1024, 0, stream>>>(x, W_ih0, W_hh0, b_ih0, b_hh0,
                                          W_ih1, W_hh1, b_ih1, b_hh1,
                                          fc_w, fc_b, out);
}